// Round 4
// baseline (174.650 us; speedup 1.0000x reference)
//
#include <hip/hip_runtime.h>

typedef _Float16 half8  __attribute__((ext_vector_type(8)));
typedef _Float16 half4v __attribute__((ext_vector_type(4)));
typedef float    floatx4 __attribute__((ext_vector_type(4)));

#define K_DIM 2312
#define KP    2368          // K padded to 74*32 = 37*64
#define N_DIM 1024
#define M_DIM 16384
#define T_DIM 16
#define O_DIM 10
#define NT64  37            // KP / 64
#define NT_OLD 73
#define LDP 40

// =====================================================================
// cvt: fp32 -> fp16 with K zero-pad to 2368
// =====================================================================
__global__ __launch_bounds__(256) void cvt_f32_f16_pad(const float* __restrict__ src,
                                                       _Float16* __restrict__ dst) {
  int row = blockIdx.x;
  const float* s = src + (size_t)row * K_DIM;
  _Float16* d = dst + (size_t)row * KP;
  for (int c = threadIdx.x; c < 296; c += 256) {
    half8 o;
    if (c < 289) {
      floatx4 a = *(const floatx4*)(s + c * 8);
      floatx4 b = *(const floatx4*)(s + c * 8 + 4);
      #pragma unroll
      for (int e = 0; e < 4; ++e) { o[e] = (_Float16)a[e]; o[4 + e] = (_Float16)b[e]; }
    } else {
      o = half8{0, 0, 0, 0, 0, 0, 0, 0};
    }
    *(half8*)(d + c * 8) = o;
  }
}

// =====================================================================
// GEMM: h[M,N] = xh[M,KP] @ w1h[N,KP]^T + b1
// 256x256 tile, BK=64 (2 K-halves of 32), 8 waves (2Mx4N), 2-slot LDS,
// 4 phases/K-tile: {stage 1 half || ds_read subtile, barrier,
//                   setprio MFMA x16, barrier}, vmcnt(4) at P2/P4.
// FIFO (per thread, 2 loads/phase): ...t.A0,t.B0,t.A1,t.B1,t1.A0,...
//   P1 of t needs t.A0^t.B0 : retired by t-1 P4's vmcnt(4)+barrier
//   P3 of t needs t.A1^t.B1 : retired by t   P2's vmcnt(4)+barrier
// =====================================================================
__device__ __forceinline__ void gload16(const _Float16* g, _Float16* l) {
  __builtin_amdgcn_global_load_lds((const __attribute__((address_space(1))) void*)g,
                                   (__attribute__((address_space(3))) void*)l, 16, 0, 0);
}

__global__ __launch_bounds__(512, 2) void gemm_f16_256(const _Float16* __restrict__ A,
                                                       const _Float16* __restrict__ Bw,
                                                       const float* __restrict__ b1,
                                                       float* __restrict__ h) {
  // [slot][khalf][256 rows * 32 halfs] ; 64 KiB each, 128 KiB total
  __shared__ __align__(16) _Float16 As[2][2][256 * 32];
  __shared__ __align__(16) _Float16 Bs[2][2][256 * 32];

  const int tid  = threadIdx.x;
  const int lane = tid & 63;
  const int w    = tid >> 6;          // 0..7
  const int wm   = (w >> 2) * 128;    // 2 row-waves
  const int wn   = (w & 3) * 64;      // 4 col-waves
  const int bm   = blockIdx.x & 63;   // same-bm blocks share an XCD (A-panel L2-resident)
  const int bn   = blockIdx.x >> 6;
  const int m0   = bm * 256;
  const int n0   = bn * 256;

  // staging geometry: wave w stages rows [w*32, w*32+32) of each half-tile
  const int rlo = lane >> 2;                 // row within 16-row group
  const int key = (rlo >> 1) & 3;            // swizzle key = ((row mod 16)>>1)&3
  const int cch = (lane & 3) ^ key;          // inverse-swizzled global k-chunk
  const _Float16* ag = A  + (size_t)(m0 + w * 32 + rlo) * KP + cch * 8;
  const _Float16* bg = Bw + (size_t)(n0 + w * 32 + rlo) * KP + cch * 8;
  const int stb = (w * 32) * 32;             // wave-uniform LDS base (halfs)

  floatx4 acc[8][4];
  #pragma unroll
  for (int i = 0; i < 8; ++i)
    #pragma unroll
    for (int j = 0; j < 4; ++j)
      acc[i][j] = floatx4{0.f, 0.f, 0.f, 0.f};

  // fragment read offsets within one (256x32) K-half
  const int fr  = lane & 15;
  const int g   = lane >> 4;
  const int rds = (g ^ ((fr >> 1) & 3)) * 8;   // swizzled 16B slot (halfs)
  int offA[8], offB[4];
  #pragma unroll
  for (int i = 0; i < 8; ++i) offA[i] = (wm + i * 16 + fr) * 32 + rds;
  #pragma unroll
  for (int j = 0; j < 4; ++j) offB[j] = (wn + j * 16 + fr) * 32 + rds;

#define STAGE_A(slot, kh, tk) do {                                        \
    const _Float16* gp = ag + (tk) * 64 + (kh) * 32;                      \
    _Float16* lp = &As[slot][kh][stb];                                    \
    gload16(gp, lp);                                                      \
    gload16(gp + 16 * KP, lp + 16 * 32);                                  \
  } while (0)
#define STAGE_B(slot, kh, tk) do {                                        \
    const _Float16* gp = bg + (tk) * 64 + (kh) * 32;                      \
    _Float16* lp = &Bs[slot][kh][stb];                                    \
    gload16(gp, lp);                                                      \
    gload16(gp + 16 * KP, lp + 16 * 32);                                  \
  } while (0)

  // prologue: stage tile 0 (FIFO: A0,B0,A1,B1); publish first K-half pair
  STAGE_A(0, 0, 0); STAGE_B(0, 0, 0); STAGE_A(0, 1, 0); STAGE_B(0, 1, 0);
  asm volatile("s_waitcnt vmcnt(4)" ::: "memory");   // t0.A0,t0.B0 landed
  __builtin_amdgcn_sched_barrier(0);
  __builtin_amdgcn_s_barrier();

  half8 af[4], bf[4];

  for (int t = 0; t < NT64; ++t) {
    const int c  = t & 1;
    const int nx = c ^ 1;
    const bool pf = (t + 1 < NT64);

    // ---------------- P1: read (i0-3, s0) + B(s0); stage t+1.A0 ----------------
    if (pf) STAGE_A(nx, 0, t + 1);
    #pragma unroll
    for (int i = 0; i < 4; ++i) af[i] = *(const half8*)(&As[c][0][offA[i]]);
    #pragma unroll
    for (int j = 0; j < 4; ++j) bf[j] = *(const half8*)(&Bs[c][0][offB[j]]);
    __builtin_amdgcn_s_barrier();
    __builtin_amdgcn_s_setprio(1);
    #pragma unroll
    for (int i = 0; i < 4; ++i)
      #pragma unroll
      for (int j = 0; j < 4; ++j)
        acc[i][j] = __builtin_amdgcn_mfma_f32_16x16x32_f16(af[i], bf[j], acc[i][j], 0, 0, 0);
    __builtin_amdgcn_s_setprio(0);
    __builtin_amdgcn_s_barrier();

    // ---------------- P2: read (i4-7, s0); stage t+1.B0; vmcnt(4) -> t.A1,t.B1 ----
    if (pf) STAGE_B(nx, 0, t + 1);
    #pragma unroll
    for (int i = 0; i < 4; ++i) af[i] = *(const half8*)(&As[c][0][offA[4 + i]]);
    if (pf) { asm volatile("s_waitcnt vmcnt(4)" ::: "memory"); }
    else    { asm volatile("s_waitcnt vmcnt(0)" ::: "memory"); }
    __builtin_amdgcn_sched_barrier(0);
    __builtin_amdgcn_s_barrier();
    __builtin_amdgcn_s_setprio(1);
    #pragma unroll
    for (int i = 0; i < 4; ++i)
      #pragma unroll
      for (int j = 0; j < 4; ++j)
        acc[4 + i][j] = __builtin_amdgcn_mfma_f32_16x16x32_f16(af[i], bf[j], acc[4 + i][j], 0, 0, 0);
    __builtin_amdgcn_s_setprio(0);
    __builtin_amdgcn_s_barrier();

    // ---------------- P3: read (i0-3, s1) + B(s1); stage t+1.A1 ----------------
    if (pf) STAGE_A(nx, 1, t + 1);
    #pragma unroll
    for (int i = 0; i < 4; ++i) af[i] = *(const half8*)(&As[c][1][offA[i]]);
    #pragma unroll
    for (int j = 0; j < 4; ++j) bf[j] = *(const half8*)(&Bs[c][1][offB[j]]);
    __builtin_amdgcn_s_barrier();
    __builtin_amdgcn_s_setprio(1);
    #pragma unroll
    for (int i = 0; i < 4; ++i)
      #pragma unroll
      for (int j = 0; j < 4; ++j)
        acc[i][j] = __builtin_amdgcn_mfma_f32_16x16x32_f16(af[i], bf[j], acc[i][j], 0, 0, 0);
    __builtin_amdgcn_s_setprio(0);
    __builtin_amdgcn_s_barrier();

    // ---------------- P4: read (i4-7, s1); stage t+1.B1; vmcnt(4) -> t+1.A0,B0 ----
    if (pf) STAGE_B(nx, 1, t + 1);
    #pragma unroll
    for (int i = 0; i < 4; ++i) af[i] = *(const half8*)(&As[c][1][offA[4 + i]]);
    if (pf) {
      asm volatile("s_waitcnt vmcnt(4)" ::: "memory");
      __builtin_amdgcn_sched_barrier(0);
    }
    __builtin_amdgcn_s_barrier();
    __builtin_amdgcn_s_setprio(1);
    #pragma unroll
    for (int i = 0; i < 4; ++i)
      #pragma unroll
      for (int j = 0; j < 4; ++j)
        acc[4 + i][j] = __builtin_amdgcn_mfma_f32_16x16x32_f16(af[i], bf[j], acc[4 + i][j], 0, 0, 0);
    __builtin_amdgcn_s_setprio(0);
    __builtin_amdgcn_s_barrier();
  }
#undef STAGE_A
#undef STAGE_B

  // epilogue: C/D layout col = lane&15, row = (lane>>4)*4 + reg
  const int cr = (lane >> 4) * 4;
  #pragma unroll
  for (int j = 0; j < 4; ++j) {
    int col = n0 + wn + j * 16 + fr;
    float bv = b1[col];
    #pragma unroll
    for (int i = 0; i < 8; ++i) {
      int rbase = m0 + wm + i * 16 + cr;
      #pragma unroll
      for (int e = 0; e < 4; ++e)
        h[(size_t)(rbase + e) * N_DIM + col] = acc[i][j][e] + bv;
    }
  }
}

// =====================================================================
// Fallback (R1): reg-staged fp32->fp16 GEMM, used only if ws too small
// =====================================================================
__device__ __forceinline__ void stage_load(const float* __restrict__ x,
                                           const float* __restrict__ w,
                                           int m0, int n0, int k0, int tid,
                                           floatx4 (&ar)[4], floatx4 (&br)[4]) {
  int r = tid >> 3;
  int c = (tid & 7) * 4;
  bool ok = (k0 + c) < K_DIM;
  #pragma unroll
  for (int i = 0; i < 4; ++i) {
    int row = r + 32 * i;
    if (ok) {
      ar[i] = *(const floatx4*)(x + (size_t)(m0 + row) * K_DIM + k0 + c);
      br[i] = *(const floatx4*)(w + (size_t)(n0 + row) * K_DIM + k0 + c);
    } else {
      ar[i] = floatx4{0.f, 0.f, 0.f, 0.f};
      br[i] = floatx4{0.f, 0.f, 0.f, 0.f};
    }
  }
}

__device__ __forceinline__ void stage_write(_Float16* __restrict__ Ab,
                                            _Float16* __restrict__ Bb, int tid,
                                            const floatx4 (&ar)[4], const floatx4 (&br)[4]) {
  int r = tid >> 3;
  int c = (tid & 7) * 4;
  #pragma unroll
  for (int i = 0; i < 4; ++i) {
    int row = r + 32 * i;
    half4v av, bv;
    #pragma unroll
    for (int e = 0; e < 4; ++e) {
      av[e] = (_Float16)ar[i][e];
      bv[e] = (_Float16)br[i][e];
    }
    *(half4v*)(Ab + row * LDP + c) = av;
    *(half4v*)(Bb + row * LDP + c) = bv;
  }
}

__global__ __launch_bounds__(256) void gemm1_kernel(const float* __restrict__ x,
                                                    const float* __restrict__ W1,
                                                    const float* __restrict__ b1,
                                                    float* __restrict__ h) {
  __shared__ _Float16 Al[2][128 * LDP];
  __shared__ _Float16 Bl[2][128 * LDP];

  int tid  = threadIdx.x;
  int lane = tid & 63;
  int w    = tid >> 6;
  int wm   = (w >> 1) * 64;
  int wn   = (w & 1) * 64;
  int m0   = (blockIdx.x >> 3) * 128;
  int n0   = (blockIdx.x & 7) * 128;

  floatx4 acc[4][4];
  #pragma unroll
  for (int i = 0; i < 4; ++i)
    #pragma unroll
    for (int j = 0; j < 4; ++j)
      acc[i][j] = floatx4{0.f, 0.f, 0.f, 0.f};

  floatx4 ar[4], br[4];
  stage_load(x, W1, m0, n0, 0, tid, ar, br);
  stage_write(Al[0], Bl[0], tid, ar, br);
  __syncthreads();

  int fr = lane & 15;
  int kc = (lane >> 4) * 8;

  int cur = 0;
  for (int kt = 0; kt < NT_OLD; ++kt) {
    if (kt + 1 < NT_OLD) stage_load(x, W1, m0, n0, (kt + 1) * 32, tid, ar, br);

    const _Float16* Ab = Al[cur];
    const _Float16* Bb = Bl[cur];
    half8 af[4], bf[4];
    #pragma unroll
    for (int f = 0; f < 4; ++f) {
      af[f] = *(const half8*)(Ab + (wm + f * 16 + fr) * LDP + kc);
      bf[f] = *(const half8*)(Bb + (wn + f * 16 + fr) * LDP + kc);
    }
    #pragma unroll
    for (int i = 0; i < 4; ++i)
      #pragma unroll
      for (int j = 0; j < 4; ++j)
        acc[i][j] = __builtin_amdgcn_mfma_f32_16x16x32_f16(af[i], bf[j], acc[i][j], 0, 0, 0);

    if (kt + 1 < NT_OLD) stage_write(Al[cur ^ 1], Bl[cur ^ 1], tid, ar, br);
    __syncthreads();
    cur ^= 1;
  }

  int cr = (lane >> 4) * 4;
  #pragma unroll
  for (int j = 0; j < 4; ++j) {
    int col = n0 + wn + j * 16 + fr;
    float bv = b1[col];
    #pragma unroll
    for (int i = 0; i < 4; ++i) {
      int rbase = m0 + wm + i * 16 + cr;
      #pragma unroll
      for (int e = 0; e < 4; ++e)
        h[(size_t)(rbase + e) * N_DIM + col] = acc[i][j][e] + bv;
    }
  }
}

// =====================================================================
// temporal LIF chain, one wave per batch row
// =====================================================================
__global__ __launch_bounds__(256) void snn_temporal_kernel(const float* __restrict__ h,
                                                           const float* __restrict__ W2,
                                                           const float* __restrict__ b2,
                                                           float* __restrict__ out) {
  __shared__ float w2s[O_DIM * N_DIM];   // 40 KB
  int tid = threadIdx.x;
  for (int i = tid; i < O_DIM * N_DIM; i += 256) w2s[i] = W2[i];
  __syncthreads();

  int wave = tid >> 6;
  int lane = tid & 63;
  int b = blockIdx.x * 4 + wave;
  const float* hrow = h + (size_t)b * (T_DIM * N_DIM);
  float* orow = out + (size_t)b * (T_DIM * O_DIM);

  float v1[16];
  #pragma unroll
  for (int e = 0; e < 16; ++e) v1[e] = 0.f;
  float v2 = 0.f;
  float bias2 = (lane < O_DIM) ? b2[lane] : 0.f;

  floatx4 hv[4];
  #pragma unroll
  for (int c = 0; c < 4; ++c) hv[c] = *(const floatx4*)(hrow + c * 256 + lane * 4);

  for (int t = 0; t < T_DIM; ++t) {
    floatx4 hn[4];
    if (t + 1 < T_DIM) {
      #pragma unroll
      for (int c = 0; c < 4; ++c)
        hn[c] = *(const floatx4*)(hrow + (t + 1) * N_DIM + c * 256 + lane * 4);
    }

    float sarr[16];
    #pragma unroll
    for (int c = 0; c < 4; ++c) {
      #pragma unroll
      for (int e = 0; e < 4; ++e) {
        int ii = c * 4 + e;
        float vn = 0.9f * v1[ii] + hv[c][e];
        float s  = 1.f / (1.f + __expf(10.f - 10.f * vn));
        v1[ii] = vn * (1.f - s);
        sarr[ii] = s;
      }
    }

    float part[10];
    #pragma unroll
    for (int o = 0; o < O_DIM; ++o) {
      float a = 0.f;
      #pragma unroll
      for (int c = 0; c < 4; ++c) {
        floatx4 w4 = *(const floatx4*)&w2s[o * N_DIM + c * 256 + lane * 4];
        a += sarr[c * 4 + 0] * w4[0] + sarr[c * 4 + 1] * w4[1]
           + sarr[c * 4 + 2] * w4[2] + sarr[c * 4 + 3] * w4[3];
      }
      part[o] = a;
    }
    #pragma unroll
    for (int m = 1; m < 64; m <<= 1) {
      #pragma unroll
      for (int o = 0; o < O_DIM; ++o) part[o] += __shfl_xor(part[o], m, 64);
    }

    float po = part[0];
    #pragma unroll
    for (int o = 1; o < O_DIM; ++o) po = (lane == o) ? part[o] : po;

    if (lane < O_DIM) {
      float vo = 0.9f * v2 + po + bias2;
      float s2 = 1.f / (1.f + __expf(10.f - 10.f * vo));
      v2 = vo * (1.f - s2);
      orow[t * O_DIM + lane] = s2;
    }

    #pragma unroll
    for (int c = 0; c < 4; ++c) hv[c] = hn[c];
  }
}

extern "C" void kernel_launch(void* const* d_in, const int* in_sizes, int n_in,
                              void* d_out, int out_size, void* d_ws, size_t ws_size,
                              hipStream_t stream) {
  const float* x  = (const float*)d_in[0];
  const float* W1 = (const float*)d_in[1];
  const float* b1 = (const float*)d_in[2];
  const float* W2 = (const float*)d_in[3];
  const float* b2 = (const float*)d_in[4];
  float* out = (float*)d_out;

  float* h = (float*)d_ws;  // 64 MiB

  const size_t H_BYTES  = (size_t)M_DIM * N_DIM * 4;
  const size_t XH_BYTES = (size_t)M_DIM * KP * 2;
  const size_t WH_BYTES = (size_t)N_DIM * KP * 2;
  const size_t NEED = H_BYTES + XH_BYTES + WH_BYTES;

  if (ws_size >= NEED) {
    _Float16* xh  = (_Float16*)((char*)d_ws + H_BYTES);
    _Float16* w1h = (_Float16*)((char*)d_ws + H_BYTES + XH_BYTES);
    cvt_f32_f16_pad<<<dim3(M_DIM), dim3(256), 0, stream>>>(x, xh);
    cvt_f32_f16_pad<<<dim3(N_DIM), dim3(256), 0, stream>>>(W1, w1h);
    gemm_f16_256<<<dim3(256), dim3(512), 0, stream>>>(xh, w1h, b1, h);
  } else {
    gemm1_kernel<<<dim3(1024), dim3(256), 0, stream>>>(x, W1, b1, h);
  }
  snn_temporal_kernel<<<dim3(256), dim3(256), 0, stream>>>(h, W2, b2, out);
}

// Round 5
// 154.329 us; speedup vs baseline: 1.1317x; 1.1317x over previous
//
#include <hip/hip_runtime.h>

typedef _Float16 half8  __attribute__((ext_vector_type(8)));
typedef _Float16 half4v __attribute__((ext_vector_type(4)));
typedef float    floatx4 __attribute__((ext_vector_type(4)));

#define K_DIM 2312
#define KP    2368          // K padded to 74*32
#define N_DIM 1024
#define M_DIM 16384
#define T_DIM 16
#define O_DIM 10
#define NKT   74            // KP / 32 (BK=32 tiles)
#define NT_OLD 73
#define LDP 40

// =====================================================================
// cvt: fp32 -> fp16 with K zero-pad to 2368
// =====================================================================
__global__ __launch_bounds__(256) void cvt_f32_f16_pad(const float* __restrict__ src,
                                                       _Float16* __restrict__ dst) {
  int row = blockIdx.x;
  const float* s = src + (size_t)row * K_DIM;
  _Float16* d = dst + (size_t)row * KP;
  for (int c = threadIdx.x; c < 296; c += 256) {
    half8 o;
    if (c < 289) {
      floatx4 a = *(const floatx4*)(s + c * 8);
      floatx4 b = *(const floatx4*)(s + c * 8 + 4);
      #pragma unroll
      for (int e = 0; e < 4; ++e) { o[e] = (_Float16)a[e]; o[4 + e] = (_Float16)b[e]; }
    } else {
      o = half8{0, 0, 0, 0, 0, 0, 0, 0};
    }
    *(half8*)(d + c * 8) = o;
  }
}

// =====================================================================
// GEMM: h[M,N] = xh[M,KP] @ w1h[N,KP]^T + b1
// 256x256 tile, BK=32, 8 waves (2Mx4N), 4-slot LDS ring staged 3 ahead,
// counted vmcnt(8), ONE barrier/tile. Per-tile wave order: MFMA(t) first
// (frags read last iter), THEN ds_read frags(t+1) -> LDS pipe drains
// t+1's reads while matrix pipe finishes t (M-first overlap; WAR on
// af/bf keeps order without extra VGPRs).
// =====================================================================
__device__ __forceinline__ void gload16(const _Float16* g, _Float16* l) {
  __builtin_amdgcn_global_load_lds((const __attribute__((address_space(1))) void*)g,
                                   (__attribute__((address_space(3))) void*)l, 16, 0, 0);
}

__global__ __launch_bounds__(512, 2) void gemm_f16_256(const _Float16* __restrict__ A,
                                                       const _Float16* __restrict__ Bw,
                                                       const float* __restrict__ b1,
                                                       float* __restrict__ h) {
  __shared__ __align__(16) _Float16 As[4][256 * 32];   // 64 KiB
  __shared__ __align__(16) _Float16 Bs[4][256 * 32];   // 64 KiB

  const int tid  = threadIdx.x;
  const int lane = tid & 63;
  const int w    = tid >> 6;          // 0..7
  const int wm   = (w >> 2) * 128;    // 2 row-waves
  const int wn   = (w & 3) * 64;      // 4 col-waves
  const int bm   = blockIdx.x & 63;   // same-bm blocks share an XCD (A-panel L2-resident)
  const int bn   = blockIdx.x >> 6;
  const int m0   = bm * 256;
  const int n0   = bn * 256;

  // staging geometry: wave w stages rows [w*32, w*32+32) of A and B
  const int rlo = lane >> 2;                 // row within 16-row group
  const int key = (rlo >> 1) & 3;            // swizzle key = ((row mod 16)>>1)&3
  const int cch = (lane & 3) ^ key;          // inverse-swizzled global k-chunk
  const _Float16* ag = A  + (size_t)(m0 + w * 32 + rlo) * KP + cch * 8;
  const _Float16* bg = Bw + (size_t)(n0 + w * 32 + rlo) * KP + cch * 8;
  const int stb = (w * 32) * 32;             // wave-uniform LDS base (halfs)

  floatx4 acc[8][4];
  #pragma unroll
  for (int i = 0; i < 8; ++i)
    #pragma unroll
    for (int j = 0; j < 4; ++j)
      acc[i][j] = floatx4{0.f, 0.f, 0.f, 0.f};

  // fragment read offsets (constant; slot varies)
  const int fr  = lane & 15;
  const int g   = lane >> 4;
  const int rds = (g ^ ((fr >> 1) & 3)) * 8;   // swizzled 16B slot (halfs)
  int offA[8], offB[4];
  #pragma unroll
  for (int i = 0; i < 8; ++i) offA[i] = (wm + i * 16 + fr) * 32 + rds;
  #pragma unroll
  for (int j = 0; j < 4; ++j) offB[j] = (wn + j * 16 + fr) * 32 + rds;

  half8 af[8], bf[4];

#define STAGE(tk) do {                                                    \
    const int _s = (tk) & 3;                                              \
    gload16(ag + (tk) * 32,           &As[_s][stb]);                      \
    gload16(ag + (tk) * 32 + 16 * KP, &As[_s][stb + 16 * 32]);            \
    gload16(bg + (tk) * 32,           &Bs[_s][stb]);                      \
    gload16(bg + (tk) * 32 + 16 * KP, &Bs[_s][stb + 16 * 32]);            \
  } while (0)

#define READF(tk) do {                                                    \
    const int _s = (tk) & 3;                                              \
    _Pragma("unroll")                                                     \
    for (int _i = 0; _i < 8; ++_i) af[_i] = *(const half8*)(&As[_s][offA[_i]]); \
    _Pragma("unroll")                                                     \
    for (int _j = 0; _j < 4; ++_j) bf[_j] = *(const half8*)(&Bs[_s][offB[_j]]); \
  } while (0)

#define MFMA32 do {                                                       \
    __builtin_amdgcn_s_setprio(1);                                        \
    _Pragma("unroll")                                                     \
    for (int _i = 0; _i < 8; ++_i)                                        \
      _Pragma("unroll")                                                   \
      for (int _j = 0; _j < 4; ++_j)                                      \
        acc[_i][_j] = __builtin_amdgcn_mfma_f32_16x16x32_f16(af[_i], bf[_j], acc[_i][_j], 0, 0, 0); \
    __builtin_amdgcn_s_setprio(0);                                        \
  } while (0)

  // prologue: stage tiles 0,1,2 (12 loads); publish tile 0; read its frags
  STAGE(0); STAGE(1); STAGE(2);
  asm volatile("s_waitcnt vmcnt(8)" ::: "memory");
  __builtin_amdgcn_sched_barrier(0);
  __builtin_amdgcn_s_barrier();
  __builtin_amdgcn_sched_barrier(0);
  READF(0);

  // main loop: tiles 0 .. NKT-4
  for (int t = 0; t < NKT - 3; ++t) {
    STAGE(t + 3);                      // slot (t+3)&3 == (t-1)&3, freed by last barrier
    asm volatile("s_waitcnt vmcnt(8)" ::: "memory");   // retire S(t+1)
    __builtin_amdgcn_sched_barrier(0);
    __builtin_amdgcn_s_barrier();      // publish tile t+1
    __builtin_amdgcn_sched_barrier(0);
    MFMA32;                            // tile t (frags already in regs)
    READF(t + 1);                      // overwrite frags; LDS drains under MFMA tail
  }
  // tail: t = NKT-3, NKT-2, NKT-1
  asm volatile("s_waitcnt vmcnt(4)" ::: "memory");
  __builtin_amdgcn_sched_barrier(0);
  __builtin_amdgcn_s_barrier();
  __builtin_amdgcn_sched_barrier(0);
  MFMA32;               // NKT-3
  READF(NKT - 2);
  asm volatile("s_waitcnt vmcnt(0)" ::: "memory");
  __builtin_amdgcn_sched_barrier(0);
  __builtin_amdgcn_s_barrier();
  __builtin_amdgcn_sched_barrier(0);
  MFMA32;               // NKT-2
  READF(NKT - 1);
  __builtin_amdgcn_s_barrier();
  __builtin_amdgcn_sched_barrier(0);
  MFMA32;               // NKT-1

#undef STAGE
#undef READF
#undef MFMA32

  // epilogue: C/D layout col = lane&15, row = (lane>>4)*4 + reg
  const int cr = (lane >> 4) * 4;
  #pragma unroll
  for (int j = 0; j < 4; ++j) {
    int col = n0 + wn + j * 16 + fr;
    float bv = b1[col];
    #pragma unroll
    for (int i = 0; i < 8; ++i) {
      int rbase = m0 + wm + i * 16 + cr;
      #pragma unroll
      for (int e = 0; e < 4; ++e)
        h[(size_t)(rbase + e) * N_DIM + col] = acc[i][j][e] + bv;
    }
  }
}

// =====================================================================
// Fallback (R1): reg-staged fp32->fp16 GEMM, used only if ws too small
// =====================================================================
__device__ __forceinline__ void stage_load(const float* __restrict__ x,
                                           const float* __restrict__ w,
                                           int m0, int n0, int k0, int tid,
                                           floatx4 (&ar)[4], floatx4 (&br)[4]) {
  int r = tid >> 3;
  int c = (tid & 7) * 4;
  bool ok = (k0 + c) < K_DIM;
  #pragma unroll
  for (int i = 0; i < 4; ++i) {
    int row = r + 32 * i;
    if (ok) {
      ar[i] = *(const floatx4*)(x + (size_t)(m0 + row) * K_DIM + k0 + c);
      br[i] = *(const floatx4*)(w + (size_t)(n0 + row) * K_DIM + k0 + c);
    } else {
      ar[i] = floatx4{0.f, 0.f, 0.f, 0.f};
      br[i] = floatx4{0.f, 0.f, 0.f, 0.f};
    }
  }
}

__device__ __forceinline__ void stage_write(_Float16* __restrict__ Ab,
                                            _Float16* __restrict__ Bb, int tid,
                                            const floatx4 (&ar)[4], const floatx4 (&br)[4]) {
  int r = tid >> 3;
  int c = (tid & 7) * 4;
  #pragma unroll
  for (int i = 0; i < 4; ++i) {
    int row = r + 32 * i;
    half4v av, bv;
    #pragma unroll
    for (int e = 0; e < 4; ++e) {
      av[e] = (_Float16)ar[i][e];
      bv[e] = (_Float16)br[i][e];
    }
    *(half4v*)(Ab + row * LDP + c) = av;
    *(half4v*)(Bb + row * LDP + c) = bv;
  }
}

__global__ __launch_bounds__(256) void gemm1_kernel(const float* __restrict__ x,
                                                    const float* __restrict__ W1,
                                                    const float* __restrict__ b1,
                                                    float* __restrict__ h) {
  __shared__ _Float16 Al[2][128 * LDP];
  __shared__ _Float16 Bl[2][128 * LDP];

  int tid  = threadIdx.x;
  int lane = tid & 63;
  int w    = tid >> 6;
  int wm   = (w >> 1) * 64;
  int wn   = (w & 1) * 64;
  int m0   = (blockIdx.x >> 3) * 128;
  int n0   = (blockIdx.x & 7) * 128;

  floatx4 acc[4][4];
  #pragma unroll
  for (int i = 0; i < 4; ++i)
    #pragma unroll
    for (int j = 0; j < 4; ++j)
      acc[i][j] = floatx4{0.f, 0.f, 0.f, 0.f};

  floatx4 ar[4], br[4];
  stage_load(x, W1, m0, n0, 0, tid, ar, br);
  stage_write(Al[0], Bl[0], tid, ar, br);
  __syncthreads();

  int fr = lane & 15;
  int kc = (lane >> 4) * 8;

  int cur = 0;
  for (int kt = 0; kt < NT_OLD; ++kt) {
    if (kt + 1 < NT_OLD) stage_load(x, W1, m0, n0, (kt + 1) * 32, tid, ar, br);

    const _Float16* Ab = Al[cur];
    const _Float16* Bb = Bl[cur];
    half8 af[4], bf[4];
    #pragma unroll
    for (int f = 0; f < 4; ++f) {
      af[f] = *(const half8*)(Ab + (wm + f * 16 + fr) * LDP + kc);
      bf[f] = *(const half8*)(Bb + (wn + f * 16 + fr) * LDP + kc);
    }
    #pragma unroll
    for (int i = 0; i < 4; ++i)
      #pragma unroll
      for (int j = 0; j < 4; ++j)
        acc[i][j] = __builtin_amdgcn_mfma_f32_16x16x32_f16(af[i], bf[j], acc[i][j], 0, 0, 0);

    if (kt + 1 < NT_OLD) stage_write(Al[cur ^ 1], Bl[cur ^ 1], tid, ar, br);
    __syncthreads();
    cur ^= 1;
  }

  int cr = (lane >> 4) * 4;
  #pragma unroll
  for (int j = 0; j < 4; ++j) {
    int col = n0 + wn + j * 16 + fr;
    float bv = b1[col];
    #pragma unroll
    for (int i = 0; i < 4; ++i) {
      int rbase = m0 + wm + i * 16 + cr;
      #pragma unroll
      for (int e = 0; e < 4; ++e)
        h[(size_t)(rbase + e) * N_DIM + col] = acc[i][j][e] + bv;
    }
  }
}

// =====================================================================
// temporal LIF chain, one wave per batch row
// =====================================================================
__global__ __launch_bounds__(256) void snn_temporal_kernel(const float* __restrict__ h,
                                                           const float* __restrict__ W2,
                                                           const float* __restrict__ b2,
                                                           float* __restrict__ out) {
  __shared__ float w2s[O_DIM * N_DIM];   // 40 KB
  int tid = threadIdx.x;
  for (int i = tid; i < O_DIM * N_DIM; i += 256) w2s[i] = W2[i];
  __syncthreads();

  int wave = tid >> 6;
  int lane = tid & 63;
  int b = blockIdx.x * 4 + wave;
  const float* hrow = h + (size_t)b * (T_DIM * N_DIM);
  float* orow = out + (size_t)b * (T_DIM * O_DIM);

  float v1[16];
  #pragma unroll
  for (int e = 0; e < 16; ++e) v1[e] = 0.f;
  float v2 = 0.f;
  float bias2 = (lane < O_DIM) ? b2[lane] : 0.f;

  floatx4 hv[4];
  #pragma unroll
  for (int c = 0; c < 4; ++c) hv[c] = *(const floatx4*)(hrow + c * 256 + lane * 4);

  for (int t = 0; t < T_DIM; ++t) {
    floatx4 hn[4];
    if (t + 1 < T_DIM) {
      #pragma unroll
      for (int c = 0; c < 4; ++c)
        hn[c] = *(const floatx4*)(hrow + (t + 1) * N_DIM + c * 256 + lane * 4);
    }

    float sarr[16];
    #pragma unroll
    for (int c = 0; c < 4; ++c) {
      #pragma unroll
      for (int e = 0; e < 4; ++e) {
        int ii = c * 4 + e;
        float vn = 0.9f * v1[ii] + hv[c][e];
        float s  = 1.f / (1.f + __expf(10.f - 10.f * vn));
        v1[ii] = vn * (1.f - s);
        sarr[ii] = s;
      }
    }

    float part[10];
    #pragma unroll
    for (int o = 0; o < O_DIM; ++o) {
      float a = 0.f;
      #pragma unroll
      for (int c = 0; c < 4; ++c) {
        floatx4 w4 = *(const floatx4*)&w2s[o * N_DIM + c * 256 + lane * 4];
        a += sarr[c * 4 + 0] * w4[0] + sarr[c * 4 + 1] * w4[1]
           + sarr[c * 4 + 2] * w4[2] + sarr[c * 4 + 3] * w4[3];
      }
      part[o] = a;
    }
    #pragma unroll
    for (int m = 1; m < 64; m <<= 1) {
      #pragma unroll
      for (int o = 0; o < O_DIM; ++o) part[o] += __shfl_xor(part[o], m, 64);
    }

    float po = part[0];
    #pragma unroll
    for (int o = 1; o < O_DIM; ++o) po = (lane == o) ? part[o] : po;

    if (lane < O_DIM) {
      float vo = 0.9f * v2 + po + bias2;
      float s2 = 1.f / (1.f + __expf(10.f - 10.f * vo));
      v2 = vo * (1.f - s2);
      orow[t * O_DIM + lane] = s2;
    }

    #pragma unroll
    for (int c = 0; c < 4; ++c) hv[c] = hn[c];
  }
}

extern "C" void kernel_launch(void* const* d_in, const int* in_sizes, int n_in,
                              void* d_out, int out_size, void* d_ws, size_t ws_size,
                              hipStream_t stream) {
  const float* x  = (const float*)d_in[0];
  const float* W1 = (const float*)d_in[1];
  const float* b1 = (const float*)d_in[2];
  const float* W2 = (const float*)d_in[3];
  const float* b2 = (const float*)d_in[4];
  float* out = (float*)d_out;

  float* h = (float*)d_ws;  // 64 MiB

  const size_t H_BYTES  = (size_t)M_DIM * N_DIM * 4;
  const size_t XH_BYTES = (size_t)M_DIM * KP * 2;
  const size_t WH_BYTES = (size_t)N_DIM * KP * 2;
  const size_t NEED = H_BYTES + XH_BYTES + WH_BYTES;

  if (ws_size >= NEED) {
    _Float16* xh  = (_Float16*)((char*)d_ws + H_BYTES);
    _Float16* w1h = (_Float16*)((char*)d_ws + H_BYTES + XH_BYTES);
    cvt_f32_f16_pad<<<dim3(M_DIM), dim3(256), 0, stream>>>(x, xh);
    cvt_f32_f16_pad<<<dim3(N_DIM), dim3(256), 0, stream>>>(W1, w1h);
    gemm_f16_256<<<dim3(256), dim3(512), 0, stream>>>(xh, w1h, b1, h);
  } else {
    gemm1_kernel<<<dim3(1024), dim3(256), 0, stream>>>(x, W1, b1, h);
  }
  snn_temporal_kernel<<<dim3(256), dim3(256), 0, stream>>>(h, W2, b2, out);
}

// Round 6
// 143.466 us; speedup vs baseline: 1.2174x; 1.0757x over previous
//
#include <hip/hip_runtime.h>

typedef _Float16 half8  __attribute__((ext_vector_type(8)));
typedef _Float16 half4v __attribute__((ext_vector_type(4)));
typedef float    floatx4 __attribute__((ext_vector_type(4)));

#define K_DIM 2312
#define KP    2368          // W1 fp16 padded K (74*32)
#define N_DIM 1024
#define M_DIM 16384
#define T_DIM 16
#define O_DIM 10
#define NKT   73            // tiles of BK=32 covering 2312 (tile 72 partial, masked)
#define NT_OLD 73
#define LDP 40

// =====================================================================
// cvt: fp32 -> fp16 with K zero-pad to 2368 (used for W1 only now)
// =====================================================================
__global__ __launch_bounds__(256) void cvt_f32_f16_pad(const float* __restrict__ src,
                                                       _Float16* __restrict__ dst) {
  int row = blockIdx.x;
  const float* s = src + (size_t)row * K_DIM;
  _Float16* d = dst + (size_t)row * KP;
  for (int c = threadIdx.x; c < 296; c += 256) {
    half8 o;
    if (c < 289) {
      floatx4 a = *(const floatx4*)(s + c * 8);
      floatx4 b = *(const floatx4*)(s + c * 8 + 4);
      #pragma unroll
      for (int e = 0; e < 4; ++e) { o[e] = (_Float16)a[e]; o[4 + e] = (_Float16)b[e]; }
    } else {
      o = half8{0, 0, 0, 0, 0, 0, 0, 0};
    }
    *(half8*)(d + c * 8) = o;
  }
}

// =====================================================================
// GEMM: h[M,N] = x[M,K](fp32, converted in-kernel) @ w1h[N,KP]^T + b1
// 256x256 tile, BK=32, 8 waves (2Mx4N).
// A: reg-staged (global fp32 -> cvt fp16 -> swizzled ds_write), 2 LDS slots,
//    issue-early/write-late (T14), two 8-float reg sets L/M.
// B: global_load_lds fp16 from w1h, 3 LDS slots, 2-ahead.
// Counted vmcnt: per iter vmcnt(4) [L landed], vmcnt(4) [M landed],
// vmcnt(6) [B(t+1) landed]; lgkmcnt(0)+s_barrier publishes tile t+1.
// M-first: MFMA(t) on frags read last iter, then READF(t+1).
// =====================================================================
__device__ __forceinline__ void gload16(const _Float16* g, _Float16* l) {
  __builtin_amdgcn_global_load_lds((const __attribute__((address_space(1))) void*)g,
                                   (__attribute__((address_space(3))) void*)l, 16, 0, 0);
}

__device__ __forceinline__ half8 cvt8(floatx4 a, floatx4 b) {
  half8 r;
  #pragma unroll
  for (int e = 0; e < 4; ++e) { r[e] = (_Float16)a[e]; r[4 + e] = (_Float16)b[e]; }
  return r;
}

__device__ __forceinline__ half8 cvt8_masked(floatx4 a, floatx4 b, int kbase) {
  half8 r;
  #pragma unroll
  for (int e = 0; e < 4; ++e) {
    r[e]     = (kbase + e     < K_DIM) ? (_Float16)a[e] : (_Float16)0.f;
    r[4 + e] = (kbase + 4 + e < K_DIM) ? (_Float16)b[e] : (_Float16)0.f;
  }
  return r;
}

__global__ __launch_bounds__(512, 2) void gemm_fused(const float* __restrict__ X,
                                                     const _Float16* __restrict__ Bw,
                                                     const float* __restrict__ b1,
                                                     float* __restrict__ h) {
  __shared__ __align__(16) _Float16 As[2][256 * 32];   // 32 KiB (fp16 A, 2 slots)
  __shared__ __align__(16) _Float16 Bs[3][256 * 32];   // 48 KiB (fp16 B, 3 slots)

  const int tid  = threadIdx.x;
  const int lane = tid & 63;
  const int w    = tid >> 6;
  const int wm   = (w >> 2) * 128;
  const int wn   = (w & 3) * 64;
  const int bm   = blockIdx.x & 63;   // same-bm blocks (4 bn) share an XCD -> x panel L2-resident
  const int bn   = blockIdx.x >> 6;
  const int m0   = bm * 256;
  const int n0   = bn * 256;

  // ---- A staging geometry (reg->cvt->LDS), thread covers row rA, 16 k's ----
  const int rA   = tid >> 1;            // 0..255
  const int kA   = (tid & 1) * 16;      // 0 or 16
  const int keyA = (rA >> 1) & 3;       // swizzle key (matches read side)
  const int gA   = kA >> 3;             // logical granule of part0 (0 or 2)
  const float* xa = X + (size_t)(m0 + rA) * K_DIM;
  const int dstA0 = rA * 32 + ((gA    ) ^ keyA) * 8;   // halfs, slot-relative
  const int dstA1 = rA * 32 + ((gA + 1) ^ keyA) * 8;

  // ---- B staging geometry (gload_lds, pre-swizzled global source) ----
  const int rlo  = lane >> 2;
  const int keyB = (rlo >> 1) & 3;
  const int cch  = (lane & 3) ^ keyB;
  const _Float16* bg = Bw + (size_t)(n0 + w * 32 + rlo) * KP + cch * 8;
  const int stbB = (w * 32) * 32;

  floatx4 acc[8][4];
  #pragma unroll
  for (int i = 0; i < 8; ++i)
    #pragma unroll
    for (int j = 0; j < 4; ++j)
      acc[i][j] = floatx4{0.f, 0.f, 0.f, 0.f};

  // ---- fragment read offsets (swizzled granule read) ----
  const int fr  = lane & 15;
  const int g   = lane >> 4;
  const int rds = (g ^ ((fr >> 1) & 3)) * 8;
  int offA[8], offB[4];
  #pragma unroll
  for (int i = 0; i < 8; ++i) offA[i] = (wm + i * 16 + fr) * 32 + rds;
  #pragma unroll
  for (int j = 0; j < 4; ++j) offB[j] = (wn + j * 16 + fr) * 32 + rds;

  half8 af[8], bf[4];
  floatx4 L0, L1, M0v, M1v;   // two in-flight A reg sets (8 floats each)

#define CLAMPK(k) ((k) > (K_DIM - 4) ? (K_DIM - 4) : (k))
#define LOADL(ts) do { int _k = (ts) * 32 + kA;                              \
    L0  = *(const floatx4*)(xa + CLAMPK(_k));                                \
    L1  = *(const floatx4*)(xa + CLAMPK(_k + 4)); } while (0)
#define LOADM(ts) do { int _k = (ts) * 32 + kA + 8;                          \
    M0v = *(const floatx4*)(xa + CLAMPK(_k));                                \
    M1v = *(const floatx4*)(xa + CLAMPK(_k + 4)); } while (0)
#define STAGEB(ts) do { const int _s = (ts) % 3;                             \
    gload16(bg + (ts) * 32,           &Bs[_s][stbB]);                        \
    gload16(bg + (ts) * 32 + 16 * KP, &Bs[_s][stbB + 16 * 32]); } while (0)

#define READF(tk) do {                                                       \
    const _Float16* _A = As[(tk) & 1];                                       \
    const _Float16* _B = Bs[(tk) % 3];                                       \
    _Pragma("unroll")                                                        \
    for (int _i = 0; _i < 8; ++_i) af[_i] = *(const half8*)(&_A[offA[_i]]);  \
    _Pragma("unroll")                                                        \
    for (int _j = 0; _j < 4; ++_j) bf[_j] = *(const half8*)(&_B[offB[_j]]);  \
  } while (0)

#define MFMA32 do {                                                          \
    __builtin_amdgcn_s_setprio(1);                                           \
    _Pragma("unroll")                                                        \
    for (int _i = 0; _i < 8; ++_i)                                           \
      _Pragma("unroll")                                                      \
      for (int _j = 0; _j < 4; ++_j)                                         \
        acc[_i][_j] = __builtin_amdgcn_mfma_f32_16x16x32_f16(af[_i], bf[_j], acc[_i][_j], 0, 0, 0); \
    __builtin_amdgcn_s_setprio(0);                                           \
  } while (0)

  // ---- prologue: tile 0 into As[0]/Bs[0]; prefetch tile 1 ----
  LOADL(0); LOADM(0);
  asm volatile("s_waitcnt vmcnt(0)" ::: "memory");
  __builtin_amdgcn_sched_barrier(0);
  *(half8*)(&As[0][dstA0]) = cvt8(L0, L1);
  *(half8*)(&As[0][dstA1]) = cvt8(M0v, M1v);
  STAGEB(0);
  LOADL(1); LOADM(1);
  STAGEB(1);
  asm volatile("s_waitcnt vmcnt(0)" ::: "memory");
  __builtin_amdgcn_sched_barrier(0);
  asm volatile("s_waitcnt lgkmcnt(0)" ::: "memory");
  __builtin_amdgcn_sched_barrier(0);
  __builtin_amdgcn_s_barrier();
  __builtin_amdgcn_sched_barrier(0);
  READF(0);

  // ---- main loop: t = 0..NKT-3 (stages tiles t+2 <= 72) ----
  for (int t = 0; t < NKT - 2; ++t) {
    const int wsl = (t + 1) & 1;      // As slot being written (tile t+1)
    // L set: tile t+1 part0
    asm volatile("s_waitcnt vmcnt(4)" ::: "memory");
    __builtin_amdgcn_sched_barrier(0);
    *(half8*)(&As[wsl][dstA0]) = cvt8(L0, L1);
    LOADL(t + 2);
    __builtin_amdgcn_sched_barrier(0);
    // M set: tile t+1 part1
    asm volatile("s_waitcnt vmcnt(4)" ::: "memory");
    __builtin_amdgcn_sched_barrier(0);
    *(half8*)(&As[wsl][dstA1]) = cvt8(M0v, M1v);
    LOADM(t + 2);
    STAGEB(t + 2);
    __builtin_amdgcn_sched_barrier(0);
    // B(t+1) landed; publish tile t+1
    asm volatile("s_waitcnt vmcnt(6)" ::: "memory");
    __builtin_amdgcn_sched_barrier(0);
    asm volatile("s_waitcnt lgkmcnt(0)" ::: "memory");
    __builtin_amdgcn_sched_barrier(0);
    __builtin_amdgcn_s_barrier();
    __builtin_amdgcn_sched_barrier(0);
    MFMA32;          // tile t (frags in regs)
    READF(t + 1);    // LDS pipe drains under MFMA tail
  }

  // ---- tail iter t = NKT-2 = 71: write tile 72 (masked), no staging ----
  {
    const int kb = (NKT - 1) * 32 + kA;   // 2304 + kA
    asm volatile("s_waitcnt vmcnt(4)" ::: "memory");
    __builtin_amdgcn_sched_barrier(0);
    *(half8*)(&As[(NKT - 1) & 1][dstA0]) = cvt8_masked(L0, L1, kb);
    asm volatile("s_waitcnt vmcnt(2)" ::: "memory");
    __builtin_amdgcn_sched_barrier(0);
    *(half8*)(&As[(NKT - 1) & 1][dstA1]) = cvt8_masked(M0v, M1v, kb + 8);
    asm volatile("s_waitcnt vmcnt(0)" ::: "memory");
    __builtin_amdgcn_sched_barrier(0);
    asm volatile("s_waitcnt lgkmcnt(0)" ::: "memory");
    __builtin_amdgcn_sched_barrier(0);
    __builtin_amdgcn_s_barrier();
    __builtin_amdgcn_sched_barrier(0);
    MFMA32;             // tile 71
    READF(NKT - 1);     // tile 72
  }
  MFMA32;               // tile 72

#undef CLAMPK
#undef LOADL
#undef LOADM
#undef STAGEB
#undef READF
#undef MFMA32

  // ---- epilogue: C/D layout col = lane&15, row = (lane>>4)*4 + reg ----
  const int cr = (lane >> 4) * 4;
  #pragma unroll
  for (int j = 0; j < 4; ++j) {
    int col = n0 + wn + j * 16 + fr;
    float bv = b1[col];
    #pragma unroll
    for (int i = 0; i < 8; ++i) {
      int rbase = m0 + wm + i * 16 + cr;
      #pragma unroll
      for (int e = 0; e < 4; ++e)
        h[(size_t)(rbase + e) * N_DIM + col] = acc[i][j][e] + bv;
    }
  }
}

// =====================================================================
// Fallback (R1): reg-staged fp32->fp16 GEMM, used only if ws too small
// =====================================================================
__device__ __forceinline__ void stage_load(const float* __restrict__ x,
                                           const float* __restrict__ w,
                                           int m0, int n0, int k0, int tid,
                                           floatx4 (&ar)[4], floatx4 (&br)[4]) {
  int r = tid >> 3;
  int c = (tid & 7) * 4;
  bool ok = (k0 + c) < K_DIM;
  #pragma unroll
  for (int i = 0; i < 4; ++i) {
    int row = r + 32 * i;
    if (ok) {
      ar[i] = *(const floatx4*)(x + (size_t)(m0 + row) * K_DIM + k0 + c);
      br[i] = *(const floatx4*)(w + (size_t)(n0 + row) * K_DIM + k0 + c);
    } else {
      ar[i] = floatx4{0.f, 0.f, 0.f, 0.f};
      br[i] = floatx4{0.f, 0.f, 0.f, 0.f};
    }
  }
}

__device__ __forceinline__ void stage_write(_Float16* __restrict__ Ab,
                                            _Float16* __restrict__ Bb, int tid,
                                            const floatx4 (&ar)[4], const floatx4 (&br)[4]) {
  int r = tid >> 3;
  int c = (tid & 7) * 4;
  #pragma unroll
  for (int i = 0; i < 4; ++i) {
    int row = r + 32 * i;
    half4v av, bv;
    #pragma unroll
    for (int e = 0; e < 4; ++e) {
      av[e] = (_Float16)ar[i][e];
      bv[e] = (_Float16)br[i][e];
    }
    *(half4v*)(Ab + row * LDP + c) = av;
    *(half4v*)(Bb + row * LDP + c) = bv;
  }
}

__global__ __launch_bounds__(256) void gemm1_kernel(const float* __restrict__ x,
                                                    const float* __restrict__ W1,
                                                    const float* __restrict__ b1,
                                                    float* __restrict__ h) {
  __shared__ _Float16 Al[2][128 * LDP];
  __shared__ _Float16 Bl[2][128 * LDP];

  int tid  = threadIdx.x;
  int lane = tid & 63;
  int w    = tid >> 6;
  int wm   = (w >> 1) * 64;
  int wn   = (w & 1) * 64;
  int m0   = (blockIdx.x >> 3) * 128;
  int n0   = (blockIdx.x & 7) * 128;

  floatx4 acc[4][4];
  #pragma unroll
  for (int i = 0; i < 4; ++i)
    #pragma unroll
    for (int j = 0; j < 4; ++j)
      acc[i][j] = floatx4{0.f, 0.f, 0.f, 0.f};

  floatx4 ar[4], br[4];
  stage_load(x, W1, m0, n0, 0, tid, ar, br);
  stage_write(Al[0], Bl[0], tid, ar, br);
  __syncthreads();

  int fr = lane & 15;
  int kc = (lane >> 4) * 8;

  int cur = 0;
  for (int kt = 0; kt < NT_OLD; ++kt) {
    if (kt + 1 < NT_OLD) stage_load(x, W1, m0, n0, (kt + 1) * 32, tid, ar, br);

    const _Float16* Ab = Al[cur];
    const _Float16* Bb = Bl[cur];
    half8 af[4], bf[4];
    #pragma unroll
    for (int f = 0; f < 4; ++f) {
      af[f] = *(const half8*)(Ab + (wm + f * 16 + fr) * LDP + kc);
      bf[f] = *(const half8*)(Bb + (wn + f * 16 + fr) * LDP + kc);
    }
    #pragma unroll
    for (int i = 0; i < 4; ++i)
      #pragma unroll
      for (int j = 0; j < 4; ++j)
        acc[i][j] = __builtin_amdgcn_mfma_f32_16x16x32_f16(af[i], bf[j], acc[i][j], 0, 0, 0);

    if (kt + 1 < NT_OLD) stage_write(Al[cur ^ 1], Bl[cur ^ 1], tid, ar, br);
    __syncthreads();
    cur ^= 1;
  }

  int cr = (lane >> 4) * 4;
  #pragma unroll
  for (int j = 0; j < 4; ++j) {
    int col = n0 + wn + j * 16 + fr;
    float bv = b1[col];
    #pragma unroll
    for (int i = 0; i < 4; ++i) {
      int rbase = m0 + wm + i * 16 + cr;
      #pragma unroll
      for (int e = 0; e < 4; ++e)
        h[(size_t)(rbase + e) * N_DIM + col] = acc[i][j][e] + bv;
    }
  }
}

// =====================================================================
// temporal LIF chain, one wave per batch row
// =====================================================================
__global__ __launch_bounds__(256) void snn_temporal_kernel(const float* __restrict__ h,
                                                           const float* __restrict__ W2,
                                                           const float* __restrict__ b2,
                                                           float* __restrict__ out) {
  __shared__ float w2s[O_DIM * N_DIM];   // 40 KB
  int tid = threadIdx.x;
  for (int i = tid; i < O_DIM * N_DIM; i += 256) w2s[i] = W2[i];
  __syncthreads();

  int wave = tid >> 6;
  int lane = tid & 63;
  int b = blockIdx.x * 4 + wave;
  const float* hrow = h + (size_t)b * (T_DIM * N_DIM);
  float* orow = out + (size_t)b * (T_DIM * O_DIM);

  float v1[16];
  #pragma unroll
  for (int e = 0; e < 16; ++e) v1[e] = 0.f;
  float v2 = 0.f;
  float bias2 = (lane < O_DIM) ? b2[lane] : 0.f;

  floatx4 hv[4];
  #pragma unroll
  for (int c = 0; c < 4; ++c) hv[c] = *(const floatx4*)(hrow + c * 256 + lane * 4);

  for (int t = 0; t < T_DIM; ++t) {
    floatx4 hn[4];
    if (t + 1 < T_DIM) {
      #pragma unroll
      for (int c = 0; c < 4; ++c)
        hn[c] = *(const floatx4*)(hrow + (t + 1) * N_DIM + c * 256 + lane * 4);
    }

    float sarr[16];
    #pragma unroll
    for (int c = 0; c < 4; ++c) {
      #pragma unroll
      for (int e = 0; e < 4; ++e) {
        int ii = c * 4 + e;
        float vn = 0.9f * v1[ii] + hv[c][e];
        float s  = 1.f / (1.f + __expf(10.f - 10.f * vn));
        v1[ii] = vn * (1.f - s);
        sarr[ii] = s;
      }
    }

    float part[10];
    #pragma unroll
    for (int o = 0; o < O_DIM; ++o) {
      float a = 0.f;
      #pragma unroll
      for (int c = 0; c < 4; ++c) {
        floatx4 w4 = *(const floatx4*)&w2s[o * N_DIM + c * 256 + lane * 4];
        a += sarr[c * 4 + 0] * w4[0] + sarr[c * 4 + 1] * w4[1]
           + sarr[c * 4 + 2] * w4[2] + sarr[c * 4 + 3] * w4[3];
      }
      part[o] = a;
    }
    #pragma unroll
    for (int m = 1; m < 64; m <<= 1) {
      #pragma unroll
      for (int o = 0; o < O_DIM; ++o) part[o] += __shfl_xor(part[o], m, 64);
    }

    float po = part[0];
    #pragma unroll
    for (int o = 1; o < O_DIM; ++o) po = (lane == o) ? part[o] : po;

    if (lane < O_DIM) {
      float vo = 0.9f * v2 + po + bias2;
      float s2 = 1.f / (1.f + __expf(10.f - 10.f * vo));
      v2 = vo * (1.f - s2);
      orow[t * O_DIM + lane] = s2;
    }

    #pragma unroll
    for (int c = 0; c < 4; ++c) hv[c] = hn[c];
  }
}

extern "C" void kernel_launch(void* const* d_in, const int* in_sizes, int n_in,
                              void* d_out, int out_size, void* d_ws, size_t ws_size,
                              hipStream_t stream) {
  const float* x  = (const float*)d_in[0];
  const float* W1 = (const float*)d_in[1];
  const float* b1 = (const float*)d_in[2];
  const float* W2 = (const float*)d_in[3];
  const float* b2 = (const float*)d_in[4];
  float* out = (float*)d_out;

  float* h = (float*)d_ws;  // 64 MiB

  const size_t H_BYTES  = (size_t)M_DIM * N_DIM * 4;   // 67,108,864
  const size_t WH_BYTES = (size_t)N_DIM * KP * 2;      //  4,849,664
  const size_t NEED = H_BYTES + WH_BYTES;

  if (ws_size >= NEED) {
    _Float16* w1h = (_Float16*)((char*)d_ws + H_BYTES);
    cvt_f32_f16_pad<<<dim3(N_DIM), dim3(256), 0, stream>>>(W1, w1h);
    gemm_fused<<<dim3(256), dim3(512), 0, stream>>>(x, w1h, b1, h);
  } else {
    gemm1_kernel<<<dim3(1024), dim3(256), 0, stream>>>(x, W1, b1, h);
  }
  snn_temporal_kernel<<<dim3(256), dim3(256), 0, stream>>>(h, W2, b2, out);
}

// Round 7
// 142.911 us; speedup vs baseline: 1.2221x; 1.0039x over previous
//
#include <hip/hip_runtime.h>

typedef _Float16 half8  __attribute__((ext_vector_type(8)));
typedef _Float16 half4v __attribute__((ext_vector_type(4)));
typedef float    floatx4 __attribute__((ext_vector_type(4)));

#define K_DIM 2312
#define KP    2368          // W1 fp16 padded K (74*32)
#define N_DIM 1024
#define M_DIM 16384
#define T_DIM 16
#define O_DIM 10
#define NKT   73            // BK=32 tiles covering 2312 (tile 72 partial, masked)
#define NT_OLD 73
#define LDP 40

// =====================================================================
// cvt: fp32 -> fp16 with K zero-pad to 2368 (W1 only)
// =====================================================================
__global__ __launch_bounds__(256) void cvt_f32_f16_pad(const float* __restrict__ src,
                                                       _Float16* __restrict__ dst) {
  int row = blockIdx.x;
  const float* s = src + (size_t)row * K_DIM;
  _Float16* d = dst + (size_t)row * KP;
  for (int c = threadIdx.x; c < 296; c += 256) {
    half8 o;
    if (c < 289) {
      floatx4 a = *(const floatx4*)(s + c * 8);
      floatx4 b = *(const floatx4*)(s + c * 8 + 4);
      #pragma unroll
      for (int e = 0; e < 4; ++e) { o[e] = (_Float16)a[e]; o[4 + e] = (_Float16)b[e]; }
    } else {
      o = half8{0, 0, 0, 0, 0, 0, 0, 0};
    }
    *(half8*)(d + c * 8) = o;
  }
}

// =====================================================================
// GEMM: h = x(fp32, cvt in-kernel) @ w1h^T + b1.  256x256, BK=32, 8 waves.
// A: reg-staged cvt, ds_write TWO tiles ahead (3 slots) -> writes drain
//    under a full MFMA phase; completion guaranteed by counted lgkmcnt(14)
//    (in-order DS: FIFO w(t+1)x2, r(t)x12, w(t+2)x2 -> retire 2 oldest).
// B: global_load_lds 2-ahead (3 slots), vmcnt-tracked.
// Every steady-state wait is free: vmcnt(0) retires only >=1-tile-old ops.
// M-first: MFMA(t) then READF(t+1) (reads drain into next iter).
// =====================================================================
__device__ __forceinline__ void gload16(const _Float16* g, _Float16* l) {
  __builtin_amdgcn_global_load_lds((const __attribute__((address_space(1))) void*)g,
                                   (__attribute__((address_space(3))) void*)l, 16, 0, 0);
}

__device__ __forceinline__ half8 cvt8(floatx4 a, floatx4 b) {
  half8 r;
  #pragma unroll
  for (int e = 0; e < 4; ++e) { r[e] = (_Float16)a[e]; r[4 + e] = (_Float16)b[e]; }
  return r;
}

__device__ __forceinline__ half8 cvt8_masked(floatx4 a, floatx4 b, int kbase) {
  half8 r;
  #pragma unroll
  for (int e = 0; e < 4; ++e) {
    r[e]     = (kbase + e     < K_DIM) ? (_Float16)a[e] : (_Float16)0.f;
    r[4 + e] = (kbase + 4 + e < K_DIM) ? (_Float16)b[e] : (_Float16)0.f;
  }
  return r;
}

#define VMCNT(n)  asm volatile("s_waitcnt vmcnt(" #n ")" ::: "memory")
#define LGKM(n)   asm volatile("s_waitcnt lgkmcnt(" #n ")" ::: "memory")
#define SBAR      __builtin_amdgcn_sched_barrier(0)

__global__ __launch_bounds__(512, 2) void gemm_fused2(const float* __restrict__ X,
                                                      const _Float16* __restrict__ Bw,
                                                      const float* __restrict__ b1,
                                                      float* __restrict__ h) {
  __shared__ __align__(16) _Float16 As[3][256 * 32];   // 48 KiB
  __shared__ __align__(16) _Float16 Bs[3][256 * 32];   // 48 KiB

  const int tid  = threadIdx.x;
  const int lane = tid & 63;
  const int w    = tid >> 6;
  const int wm   = (w >> 2) * 128;
  const int wn   = (w & 3) * 64;
  const int bm   = blockIdx.x & 63;   // 4 bn-blocks per bm share an XCD -> x panel L2-resident
  const int bn   = blockIdx.x >> 6;
  const int m0   = bm * 256;
  const int n0   = bn * 256;

  // ---- A staging: thread covers row rA, 16 k's (4 dwordx4 -> 2 swizzled b128 writes) ----
  const int rA   = tid >> 1;            // 0..255
  const int kA   = (tid & 1) * 16;      // 0 or 16
  const int keyA = (rA >> 1) & 3;
  const int gA   = kA >> 3;             // granule of part0 (0 or 2)
  const float* xa = X + (size_t)(m0 + rA) * K_DIM;
  const int dstA0 = rA * 32 + ((gA    ) ^ keyA) * 8;
  const int dstA1 = rA * 32 + ((gA + 1) ^ keyA) * 8;

  // ---- B staging (gload_lds, pre-swizzled global source) ----
  const int rlo  = lane >> 2;
  const int keyB = (rlo >> 1) & 3;
  const int cch  = (lane & 3) ^ keyB;
  const _Float16* bg = Bw + (size_t)(n0 + w * 32 + rlo) * KP + cch * 8;
  const int stbB = (w * 32) * 32;

  floatx4 acc[8][4];
  #pragma unroll
  for (int i = 0; i < 8; ++i)
    #pragma unroll
    for (int j = 0; j < 4; ++j)
      acc[i][j] = floatx4{0.f, 0.f, 0.f, 0.f};

  // ---- fragment read offsets (swizzled granule read) ----
  const int fr  = lane & 15;
  const int g   = lane >> 4;
  const int rds = (g ^ ((fr >> 1) & 3)) * 8;
  int offA[8], offB[4];
  #pragma unroll
  for (int i = 0; i < 8; ++i) offA[i] = (wm + i * 16 + fr) * 32 + rds;
  #pragma unroll
  for (int j = 0; j < 4; ++j) offB[j] = (wn + j * 16 + fr) * 32 + rds;

  half8 af[8], bf[4];
  floatx4 L0, L1, M0v, M1v;

#define CLAMPK(k) ((k) > (K_DIM - 4) ? (K_DIM - 4) : (k))
#define LOADL(ts) do { int _k = (ts) * 32 + kA;                              \
    L0  = *(const floatx4*)(xa + CLAMPK(_k));                                \
    L1  = *(const floatx4*)(xa + CLAMPK(_k + 4)); } while (0)
#define LOADM(ts) do { int _k = (ts) * 32 + kA + 8;                          \
    M0v = *(const floatx4*)(xa + CLAMPK(_k));                                \
    M1v = *(const floatx4*)(xa + CLAMPK(_k + 4)); } while (0)
#define WRITEA(ts) do { _Float16* _d = As[(ts) % 3];                         \
    *(half8*)(&_d[dstA0]) = cvt8(L0, L1);                                    \
    *(half8*)(&_d[dstA1]) = cvt8(M0v, M1v); } while (0)
#define WRITEA_MASK(ts) do { _Float16* _d = As[(ts) % 3];                    \
    const int _kb = (ts) * 32 + kA;                                          \
    *(half8*)(&_d[dstA0]) = cvt8_masked(L0, L1, _kb);                        \
    *(half8*)(&_d[dstA1]) = cvt8_masked(M0v, M1v, _kb + 8); } while (0)
#define STAGEB(ts) do { const int _s = (ts) % 3;                             \
    gload16(bg + (ts) * 32,           &Bs[_s][stbB]);                        \
    gload16(bg + (ts) * 32 + 16 * KP, &Bs[_s][stbB + 16 * 32]); } while (0)
#define READF(tk) do {                                                       \
    const _Float16* _A = As[(tk) % 3];                                       \
    const _Float16* _B = Bs[(tk) % 3];                                       \
    _Pragma("unroll")                                                        \
    for (int _i = 0; _i < 8; ++_i) af[_i] = *(const half8*)(&_A[offA[_i]]);  \
    _Pragma("unroll")                                                        \
    for (int _j = 0; _j < 4; ++_j) bf[_j] = *(const half8*)(&_B[offB[_j]]);  \
  } while (0)
#define MFMA32 do {                                                          \
    __builtin_amdgcn_s_setprio(1);                                           \
    _Pragma("unroll")                                                        \
    for (int _i = 0; _i < 8; ++_i)                                           \
      _Pragma("unroll")                                                      \
      for (int _j = 0; _j < 4; ++_j)                                         \
        acc[_i][_j] = __builtin_amdgcn_mfma_f32_16x16x32_f16(af[_i], bf[_j], acc[_i][_j], 0, 0, 0); \
    __builtin_amdgcn_s_setprio(0);                                           \
  } while (0)

  // ---- prologue: A(0),A(1) written; B(0),B(1) staged; L/M(2) in flight ----
  LOADL(0); LOADM(0);
  VMCNT(0); SBAR;
  WRITEA(0);
  LOADL(1); LOADM(1);
  VMCNT(0); SBAR;
  WRITEA(1);
  STAGEB(0); STAGEB(1);
  LOADL(2); LOADM(2);
  VMCNT(4); SBAR;              // FIFO B0,B1,L2,M2 -> retires B(0),B(1)
  LGKM(0);  SBAR;              // A(0),A(1) written (no reads pending yet)
  __builtin_amdgcn_s_barrier(); SBAR;
  READF(0);

  // ---- main loop: t = 0..69 (writes A(t+2)<=71 full, loads t+3<=72) ----
  for (int t = 0; t < NKT - 3; ++t) {
    VMCNT(0); SBAR;            // retires L/M(t+2) + B(t+1), all >=1 tile old
    WRITEA(t + 2);             // drains under MFMA(t); guaranteed at t+1 by lgkm(14)
    LOADL(t + 3); LOADM(t + 3);
    STAGEB(t + 2);
    LGKM(14); SBAR;            // FIFO w(t+1)x2, r(t)x12, w(t+2)x2 -> retires w(t+1)
    __builtin_amdgcn_s_barrier(); SBAR;   // publish A(t+1), B(t+1)
    MFMA32;                    // tile t (frags read last iter)
    READF(t + 1);              // 12 reads drain into next iter
  }

  // ---- peel t = 70: write masked tile 72, stage B(72), no loads ----
  VMCNT(0); SBAR;              // L/M(72), B(71)
  WRITEA_MASK(NKT - 1);        // slot 0
  STAGEB(NKT - 1);             // slot 0
  LGKM(14); SBAR;              // retires w(71)
  __builtin_amdgcn_s_barrier(); SBAR;     // publish A(71), B(71)
  MFMA32;                      // tile 70
  READF(NKT - 2);              // tile 71

  // ---- peel t = 71 ----
  VMCNT(0); SBAR;              // B(72)
  LGKM(12); SBAR;              // FIFO w(72)x2, r(71)x12 -> retires w(72)
  __builtin_amdgcn_s_barrier(); SBAR;     // publish A(72), B(72)
  MFMA32;                      // tile 71
  READF(NKT - 1);              // tile 72

  MFMA32;                      // tile 72

#undef CLAMPK
#undef LOADL
#undef LOADM
#undef WRITEA
#undef WRITEA_MASK
#undef STAGEB
#undef READF
#undef MFMA32

  // ---- epilogue: C/D layout col = lane&15, row = (lane>>4)*4 + reg ----
  const int cr = (lane >> 4) * 4;
  #pragma unroll
  for (int j = 0; j < 4; ++j) {
    int col = n0 + wn + j * 16 + fr;
    float bv = b1[col];
    #pragma unroll
    for (int i = 0; i < 8; ++i) {
      int rbase = m0 + wm + i * 16 + cr;
      #pragma unroll
      for (int e = 0; e < 4; ++e)
        h[(size_t)(rbase + e) * N_DIM + col] = acc[i][j][e] + bv;
    }
  }
}

// =====================================================================
// Fallback (R1): reg-staged fp32->fp16 GEMM, used only if ws too small
// =====================================================================
__device__ __forceinline__ void stage_load(const float* __restrict__ x,
                                           const float* __restrict__ w,
                                           int m0, int n0, int k0, int tid,
                                           floatx4 (&ar)[4], floatx4 (&br)[4]) {
  int r = tid >> 3;
  int c = (tid & 7) * 4;
  bool ok = (k0 + c) < K_DIM;
  #pragma unroll
  for (int i = 0; i < 4; ++i) {
    int row = r + 32 * i;
    if (ok) {
      ar[i] = *(const floatx4*)(x + (size_t)(m0 + row) * K_DIM + k0 + c);
      br[i] = *(const floatx4*)(w + (size_t)(n0 + row) * K_DIM + k0 + c);
    } else {
      ar[i] = floatx4{0.f, 0.f, 0.f, 0.f};
      br[i] = floatx4{0.f, 0.f, 0.f, 0.f};
    }
  }
}

__device__ __forceinline__ void stage_write(_Float16* __restrict__ Ab,
                                            _Float16* __restrict__ Bb, int tid,
                                            const floatx4 (&ar)[4], const floatx4 (&br)[4]) {
  int r = tid >> 3;
  int c = (tid & 7) * 4;
  #pragma unroll
  for (int i = 0; i < 4; ++i) {
    int row = r + 32 * i;
    half4v av, bv;
    #pragma unroll
    for (int e = 0; e < 4; ++e) {
      av[e] = (_Float16)ar[i][e];
      bv[e] = (_Float16)br[i][e];
    }
    *(half4v*)(Ab + row * LDP + c) = av;
    *(half4v*)(Bb + row * LDP + c) = bv;
  }
}

__global__ __launch_bounds__(256) void gemm1_kernel(const float* __restrict__ x,
                                                    const float* __restrict__ W1,
                                                    const float* __restrict__ b1,
                                                    float* __restrict__ h) {
  __shared__ _Float16 Al[2][128 * LDP];
  __shared__ _Float16 Bl[2][128 * LDP];

  int tid  = threadIdx.x;
  int lane = tid & 63;
  int w    = tid >> 6;
  int wm   = (w >> 1) * 64;
  int wn   = (w & 1) * 64;
  int m0   = (blockIdx.x >> 3) * 128;
  int n0   = (blockIdx.x & 7) * 128;

  floatx4 acc[4][4];
  #pragma unroll
  for (int i = 0; i < 4; ++i)
    #pragma unroll
    for (int j = 0; j < 4; ++j)
      acc[i][j] = floatx4{0.f, 0.f, 0.f, 0.f};

  floatx4 ar[4], br[4];
  stage_load(x, W1, m0, n0, 0, tid, ar, br);
  stage_write(Al[0], Bl[0], tid, ar, br);
  __syncthreads();

  int fr = lane & 15;
  int kc = (lane >> 4) * 8;

  int cur = 0;
  for (int kt = 0; kt < NT_OLD; ++kt) {
    if (kt + 1 < NT_OLD) stage_load(x, W1, m0, n0, (kt + 1) * 32, tid, ar, br);

    const _Float16* Ab = Al[cur];
    const _Float16* Bb = Bl[cur];
    half8 af[4], bf[4];
    #pragma unroll
    for (int f = 0; f < 4; ++f) {
      af[f] = *(const half8*)(Ab + (wm + f * 16 + fr) * LDP + kc);
      bf[f] = *(const half8*)(Bb + (wn + f * 16 + fr) * LDP + kc);
    }
    #pragma unroll
    for (int i = 0; i < 4; ++i)
      #pragma unroll
      for (int j = 0; j < 4; ++j)
        acc[i][j] = __builtin_amdgcn_mfma_f32_16x16x32_f16(af[i], bf[j], acc[i][j], 0, 0, 0);

    if (kt + 1 < NT_OLD) stage_write(Al[cur ^ 1], Bl[cur ^ 1], tid, ar, br);
    __syncthreads();
    cur ^= 1;
  }

  int cr = (lane >> 4) * 4;
  #pragma unroll
  for (int j = 0; j < 4; ++j) {
    int col = n0 + wn + j * 16 + fr;
    float bv = b1[col];
    #pragma unroll
    for (int i = 0; i < 4; ++i) {
      int rbase = m0 + wm + i * 16 + cr;
      #pragma unroll
      for (int e = 0; e < 4; ++e)
        h[(size_t)(rbase + e) * N_DIM + col] = acc[i][j][e] + bv;
    }
  }
}

// =====================================================================
// temporal LIF chain, one wave per batch row
// =====================================================================
__global__ __launch_bounds__(256) void snn_temporal_kernel(const float* __restrict__ h,
                                                           const float* __restrict__ W2,
                                                           const float* __restrict__ b2,
                                                           float* __restrict__ out) {
  __shared__ float w2s[O_DIM * N_DIM];   // 40 KB
  int tid = threadIdx.x;
  for (int i = tid; i < O_DIM * N_DIM; i += 256) w2s[i] = W2[i];
  __syncthreads();

  int wave = tid >> 6;
  int lane = tid & 63;
  int b = blockIdx.x * 4 + wave;
  const float* hrow = h + (size_t)b * (T_DIM * N_DIM);
  float* orow = out + (size_t)b * (T_DIM * O_DIM);

  float v1[16];
  #pragma unroll
  for (int e = 0; e < 16; ++e) v1[e] = 0.f;
  float v2 = 0.f;
  float bias2 = (lane < O_DIM) ? b2[lane] : 0.f;

  floatx4 hv[4];
  #pragma unroll
  for (int c = 0; c < 4; ++c) hv[c] = *(const floatx4*)(hrow + c * 256 + lane * 4);

  for (int t = 0; t < T_DIM; ++t) {
    floatx4 hn[4];
    if (t + 1 < T_DIM) {
      #pragma unroll
      for (int c = 0; c < 4; ++c)
        hn[c] = *(const floatx4*)(hrow + (t + 1) * N_DIM + c * 256 + lane * 4);
    }

    float sarr[16];
    #pragma unroll
    for (int c = 0; c < 4; ++c) {
      #pragma unroll
      for (int e = 0; e < 4; ++e) {
        int ii = c * 4 + e;
        float vn = 0.9f * v1[ii] + hv[c][e];
        float s  = 1.f / (1.f + __expf(10.f - 10.f * vn));
        v1[ii] = vn * (1.f - s);
        sarr[ii] = s;
      }
    }

    float part[10];
    #pragma unroll
    for (int o = 0; o < O_DIM; ++o) {
      float a = 0.f;
      #pragma unroll
      for (int c = 0; c < 4; ++c) {
        floatx4 w4 = *(const floatx4*)&w2s[o * N_DIM + c * 256 + lane * 4];
        a += sarr[c * 4 + 0] * w4[0] + sarr[c * 4 + 1] * w4[1]
           + sarr[c * 4 + 2] * w4[2] + sarr[c * 4 + 3] * w4[3];
      }
      part[o] = a;
    }
    #pragma unroll
    for (int m = 1; m < 64; m <<= 1) {
      #pragma unroll
      for (int o = 0; o < O_DIM; ++o) part[o] += __shfl_xor(part[o], m, 64);
    }

    float po = part[0];
    #pragma unroll
    for (int o = 1; o < O_DIM; ++o) po = (lane == o) ? part[o] : po;

    if (lane < O_DIM) {
      float vo = 0.9f * v2 + po + bias2;
      float s2 = 1.f / (1.f + __expf(10.f - 10.f * vo));
      v2 = vo * (1.f - s2);
      orow[t * O_DIM + lane] = s2;
    }

    #pragma unroll
    for (int c = 0; c < 4; ++c) hv[c] = hn[c];
  }
}

extern "C" void kernel_launch(void* const* d_in, const int* in_sizes, int n_in,
                              void* d_out, int out_size, void* d_ws, size_t ws_size,
                              hipStream_t stream) {
  const float* x  = (const float*)d_in[0];
  const float* W1 = (const float*)d_in[1];
  const float* b1 = (const float*)d_in[2];
  const float* W2 = (const float*)d_in[3];
  const float* b2 = (const float*)d_in[4];
  float* out = (float*)d_out;

  float* h = (float*)d_ws;  // 64 MiB

  const size_t H_BYTES  = (size_t)M_DIM * N_DIM * 4;   // 67,108,864
  const size_t WH_BYTES = (size_t)N_DIM * KP * 2;      //  4,849,664
  const size_t NEED = H_BYTES + WH_BYTES;

  if (ws_size >= NEED) {
    _Float16* w1h = (_Float16*)((char*)d_ws + H_BYTES);
    cvt_f32_f16_pad<<<dim3(N_DIM), dim3(256), 0, stream>>>(W1, w1h);
    gemm_fused2<<<dim3(256), dim3(512), 0, stream>>>(x, w1h, b1, h);
  } else {
    gemm1_kernel<<<dim3(1024), dim3(256), 0, stream>>>(x, W1, b1, h);
  }
  snn_temporal_kernel<<<dim3(256), dim3(256), 0, stream>>>(h, W2, b2, out);
}

// Round 8
// 132.399 us; speedup vs baseline: 1.3191x; 1.0794x over previous
//
#include <hip/hip_runtime.h>

typedef _Float16 half8  __attribute__((ext_vector_type(8)));
typedef _Float16 half4v __attribute__((ext_vector_type(4)));
typedef float    floatx4 __attribute__((ext_vector_type(4)));

#define K_DIM 2312
#define KP    2368          // W1 fp16 padded K (74*32)
#define N_DIM 1024
#define M_DIM 16384
#define T_DIM 16
#define O_DIM 10
#define NKT   73            // BK=32 tiles covering 2312 (tile 72 partial)
#define NT_OLD 73
#define LDP 40

// =====================================================================
// cvt: fp32 -> fp16 with K zero-pad to 2368 (W1 only; pad MUST be zero --
// the GEMM's A-tail garbage relies on B==0 for k in [2312,2336))
// =====================================================================
__global__ __launch_bounds__(256) void cvt_f32_f16_pad(const float* __restrict__ src,
                                                       _Float16* __restrict__ dst) {
  int row = blockIdx.x;
  const float* s = src + (size_t)row * K_DIM;
  _Float16* d = dst + (size_t)row * KP;
  for (int c = threadIdx.x; c < 296; c += 256) {
    half8 o;
    if (c < 289) {
      floatx4 a = *(const floatx4*)(s + c * 8);
      floatx4 b = *(const floatx4*)(s + c * 8 + 4);
      #pragma unroll
      for (int e = 0; e < 4; ++e) { o[e] = (_Float16)a[e]; o[4 + e] = (_Float16)b[e]; }
    } else {
      o = half8{0, 0, 0, 0, 0, 0, 0, 0};
    }
    *(half8*)(d + c * 8) = o;
  }
}

// =====================================================================
// GEMM: h = x(fp32) @ w1h^T + b1.  256x256 tile, BK=32, 8 waves (4M x 2N).
// A staged as RAW FP32 via global_load_lds (pure vmcnt, zero lgkm ops),
// converted fp32->fp16 on the LDS->VGPR read path (RTN casts).
// R5 ring schedule: 3A+3B slots (144 KiB), stage 2 ahead, vmcnt(6),
// ONE barrier/tile, M-first (MFMA(t) then READF(t+1)).
// A swizzle: granule G = pos ^ (row&7) both sides (involution, rule #21).
// =====================================================================
__device__ __forceinline__ void gload16(const void* g, void* l) {
  __builtin_amdgcn_global_load_lds((const __attribute__((address_space(1))) void*)g,
                                   (__attribute__((address_space(3))) void*)l, 16, 0, 0);
}

#define VMCNT(n)  asm volatile("s_waitcnt vmcnt(" #n ")" ::: "memory")
#define SBAR      __builtin_amdgcn_sched_barrier(0)

__global__ __launch_bounds__(512, 2) void gemm_fused3(const float* __restrict__ X,
                                                      const _Float16* __restrict__ Bw,
                                                      const float* __restrict__ b1,
                                                      float* __restrict__ h) {
  __shared__ __align__(16) float    As[3][256 * 32];   // 3 x 32 KiB (fp32 A)
  __shared__ __align__(16) _Float16 Bs[3][256 * 32];   // 3 x 16 KiB (fp16 B)

  const int tid  = threadIdx.x;
  const int lane = tid & 63;
  const int w    = tid >> 6;          // 0..7
  const int wm   = (w >> 1) * 64;     // 4 row-waves
  const int wn   = (w & 1) * 128;     // 2 col-waves
  const int bm   = blockIdx.x & 63;
  const int bn   = blockIdx.x >> 6;
  const int m0   = bm * 256;
  const int n0   = bn * 256;

  // ---- A staging: 4 DMAs/thread; DMA d covers rows [w*32+d*8, +8) ----
  // lane -> row offset (lane>>3), granule slot (lane&7); source granule
  // G = (lane&7) ^ (lane>>3) (inverse swizzle). k clamped to <=2308.
  const int rOffA = lane >> 3;
  const int gsrcA = (lane & 7) ^ (lane >> 3);        // pre-swizzled granule
  const float* xaw = X + (size_t)(m0 + w * 32) * K_DIM;   // wave base

  // ---- B staging (unchanged from R5): 2 DMAs/thread-wave ----
  const int rlo  = lane >> 2;
  const int keyB = (rlo >> 1) & 3;
  const int cch  = (lane & 3) ^ keyB;
  const _Float16* bg = Bw + (size_t)(n0 + w * 32 + rlo) * KP + cch * 8;
  const int stbB = (w * 32) * 32;

  floatx4 acc[4][8];
  #pragma unroll
  for (int i = 0; i < 4; ++i)
    #pragma unroll
    for (int j = 0; j < 8; ++j)
      acc[i][j] = floatx4{0.f, 0.f, 0.f, 0.f};

  // ---- fragment read offsets ----
  const int fr = lane & 15;
  const int q  = lane >> 4;           // 0..3
  const int rdsB = (q ^ ((fr >> 1) & 3)) * 8;        // B swizzled 16B slot (halfs)
  int offB[8];
  #pragma unroll
  for (int j = 0; j < 8; ++j) offB[j] = (wn + j * 16 + fr) * 32 + rdsB;
  // A: frag i at row wm+i*16+fr; logical granules 2q, 2q+1 (4 floats each)
  const int cA = fr & 7;
  int offA0[4], offA1[4];
  #pragma unroll
  for (int i = 0; i < 4; ++i) {
    const int rowA = wm + i * 16 + fr;
    offA0[i] = rowA * 32 + ((2 * q)     ^ cA) * 4;   // floats
    offA1[i] = rowA * 32 + ((2 * q + 1) ^ cA) * 4;
  }

  floatx4 fA[8];     // raw fp32 A frags (frag i = fA[2i], fA[2i+1])
  half8   bf[8];

#define STAGE(tk) do {                                                       \
    const int _s = (tk) % 3;                                                 \
    _Pragma("unroll")                                                        \
    for (int _d = 0; _d < 4; ++_d) {                                         \
      int _k = (tk) * 32 + gsrcA * 4;                                        \
      _k = _k > 2308 ? 2308 : _k;                                            \
      const float* _src = xaw + (size_t)(_d * 8 + rOffA) * K_DIM + _k;       \
      gload16(_src, &As[_s][(w * 32 + _d * 8) * 32]);                        \
    }                                                                        \
    gload16(bg + (tk) * 32,           &Bs[_s][stbB]);                        \
    gload16(bg + (tk) * 32 + 16 * KP, &Bs[_s][stbB + 16 * 32]);              \
  } while (0)

#define READF(tk) do {                                                       \
    const float*    _A = As[(tk) % 3];                                       \
    const _Float16* _B = Bs[(tk) % 3];                                       \
    _Pragma("unroll")                                                        \
    for (int _i = 0; _i < 4; ++_i) {                                         \
      fA[2 * _i]     = *(const floatx4*)(&_A[offA0[_i]]);                    \
      fA[2 * _i + 1] = *(const floatx4*)(&_A[offA1[_i]]);                    \
    }                                                                        \
    _Pragma("unroll")                                                        \
    for (int _j = 0; _j < 8; ++_j) bf[_j] = *(const half8*)(&_B[offB[_j]]);  \
  } while (0)

#define MFMA32 do {                                                          \
    __builtin_amdgcn_s_setprio(1);                                           \
    _Pragma("unroll")                                                        \
    for (int _i = 0; _i < 4; ++_i) {                                         \
      half8 _ah;                                                             \
      _Pragma("unroll")                                                      \
      for (int _e = 0; _e < 4; ++_e) {                                       \
        _ah[_e]     = (_Float16)fA[2 * _i][_e];                              \
        _ah[4 + _e] = (_Float16)fA[2 * _i + 1][_e];                          \
      }                                                                      \
      _Pragma("unroll")                                                      \
      for (int _j = 0; _j < 8; ++_j)                                         \
        acc[_i][_j] = __builtin_amdgcn_mfma_f32_16x16x32_f16(_ah, bf[_j], acc[_i][_j], 0, 0, 0); \
    }                                                                        \
    __builtin_amdgcn_s_setprio(0);                                           \
  } while (0)

  // ---- prologue: stage tiles 0,1 (12 DMAs); publish tile 0; read frags ----
  STAGE(0); STAGE(1);
  VMCNT(6); SBAR;              // tile 0's 6 ops retired
  __builtin_amdgcn_s_barrier(); SBAR;
  READF(0);

  // ---- main loop: t = 0..70 (stages t+2 = 2..72) ----
  for (int t = 0; t < NKT - 2; ++t) {
    STAGE(t + 2);              // slot (t+2)%3 == (t-1)%3: reads retired an iter ago
    VMCNT(6); SBAR;            // retire tile t+1's 6 ops
    __builtin_amdgcn_s_barrier(); SBAR;   // publish tile t+1
    MFMA32;                    // tile t (frags read last iter)
    READF(t + 1);              // reads drain under next front / MFMA tail
  }

  // ---- tail: t = 71 ----
  VMCNT(0); SBAR;              // tile 72 landed
  __builtin_amdgcn_s_barrier(); SBAR;
  MFMA32;                      // tile 71
  READF(NKT - 1);              // tile 72
  MFMA32;                      // tile 72

#undef STAGE
#undef READF
#undef MFMA32

  // ---- epilogue: C/D layout col = lane&15, row = (lane>>4)*4 + reg ----
  const int cr = (lane >> 4) * 4;
  #pragma unroll
  for (int j = 0; j < 8; ++j) {
    int col = n0 + wn + j * 16 + fr;
    float bv = b1[col];
    #pragma unroll
    for (int i = 0; i < 4; ++i) {
      int rbase = m0 + wm + i * 16 + cr;
      #pragma unroll
      for (int e = 0; e < 4; ++e)
        h[(size_t)(rbase + e) * N_DIM + col] = acc[i][j][e] + bv;
    }
  }
}

// =====================================================================
// Fallback (R1): reg-staged fp32->fp16 GEMM, used only if ws too small
// =====================================================================
__device__ __forceinline__ void stage_load(const float* __restrict__ x,
                                           const float* __restrict__ w,
                                           int m0, int n0, int k0, int tid,
                                           floatx4 (&ar)[4], floatx4 (&br)[4]) {
  int r = tid >> 3;
  int c = (tid & 7) * 4;
  bool ok = (k0 + c) < K_DIM;
  #pragma unroll
  for (int i = 0; i < 4; ++i) {
    int row = r + 32 * i;
    if (ok) {
      ar[i] = *(const floatx4*)(x + (size_t)(m0 + row) * K_DIM + k0 + c);
      br[i] = *(const floatx4*)(w + (size_t)(n0 + row) * K_DIM + k0 + c);
    } else {
      ar[i] = floatx4{0.f, 0.f, 0.f, 0.f};
      br[i] = floatx4{0.f, 0.f, 0.f, 0.f};
    }
  }
}

__device__ __forceinline__ void stage_write(_Float16* __restrict__ Ab,
                                            _Float16* __restrict__ Bb, int tid,
                                            const floatx4 (&ar)[4], const floatx4 (&br)[4]) {
  int r = tid >> 3;
  int c = (tid & 7) * 4;
  #pragma unroll
  for (int i = 0; i < 4; ++i) {
    int row = r + 32 * i;
    half4v av, bv;
    #pragma unroll
    for (int e = 0; e < 4; ++e) {
      av[e] = (_Float16)ar[i][e];
      bv[e] = (_Float16)br[i][e];
    }
    *(half4v*)(Ab + row * LDP + c) = av;
    *(half4v*)(Bb + row * LDP + c) = bv;
  }
}

__global__ __launch_bounds__(256) void gemm1_kernel(const float* __restrict__ x,
                                                    const float* __restrict__ W1,
                                                    const float* __restrict__ b1,
                                                    float* __restrict__ h) {
  __shared__ _Float16 Al[2][128 * LDP];
  __shared__ _Float16 Bl[2][128 * LDP];

  int tid  = threadIdx.x;
  int lane = tid & 63;
  int w    = tid >> 6;
  int wm   = (w >> 1) * 64;
  int wn   = (w & 1) * 64;
  int m0   = (blockIdx.x >> 3) * 128;
  int n0   = (blockIdx.x & 7) * 128;

  floatx4 acc[4][4];
  #pragma unroll
  for (int i = 0; i < 4; ++i)
    #pragma unroll
    for (int j = 0; j < 4; ++j)
      acc[i][j] = floatx4{0.f, 0.f, 0.f, 0.f};

  floatx4 ar[4], br[4];
  stage_load(x, W1, m0, n0, 0, tid, ar, br);
  stage_write(Al[0], Bl[0], tid, ar, br);
  __syncthreads();

  int fr = lane & 15;
  int kc = (lane >> 4) * 8;

  int cur = 0;
  for (int kt = 0; kt < NT_OLD; ++kt) {
    if (kt + 1 < NT_OLD) stage_load(x, W1, m0, n0, (kt + 1) * 32, tid, ar, br);

    const _Float16* Ab = Al[cur];
    const _Float16* Bb = Bl[cur];
    half8 af[4], bf[4];
    #pragma unroll
    for (int f = 0; f < 4; ++f) {
      af[f] = *(const half8*)(Ab + (wm + f * 16 + fr) * LDP + kc);
      bf[f] = *(const half8*)(Bb + (wn + f * 16 + fr) * LDP + kc);
    }
    #pragma unroll
    for (int i = 0; i < 4; ++i)
      #pragma unroll
      for (int j = 0; j < 4; ++j)
        acc[i][j] = __builtin_amdgcn_mfma_f32_16x16x32_f16(af[i], bf[j], acc[i][j], 0, 0, 0);

    if (kt + 1 < NT_OLD) stage_write(Al[cur ^ 1], Bl[cur ^ 1], tid, ar, br);
    __syncthreads();
    cur ^= 1;
  }

  int cr = (lane >> 4) * 4;
  #pragma unroll
  for (int j = 0; j < 4; ++j) {
    int col = n0 + wn + j * 16 + fr;
    float bv = b1[col];
    #pragma unroll
    for (int i = 0; i < 4; ++i) {
      int rbase = m0 + wm + i * 16 + cr;
      #pragma unroll
      for (int e = 0; e < 4; ++e)
        h[(size_t)(rbase + e) * N_DIM + col] = acc[i][j][e] + bv;
    }
  }
}

// =====================================================================
// temporal LIF chain, one wave per batch row
// =====================================================================
__global__ __launch_bounds__(256) void snn_temporal_kernel(const float* __restrict__ h,
                                                           const float* __restrict__ W2,
                                                           const float* __restrict__ b2,
                                                           float* __restrict__ out) {
  __shared__ float w2s[O_DIM * N_DIM];   // 40 KB
  int tid = threadIdx.x;
  for (int i = tid; i < O_DIM * N_DIM; i += 256) w2s[i] = W2[i];
  __syncthreads();

  int wave = tid >> 6;
  int lane = tid & 63;
  int b = blockIdx.x * 4 + wave;
  const float* hrow = h + (size_t)b * (T_DIM * N_DIM);
  float* orow = out + (size_t)b * (T_DIM * O_DIM);

  float v1[16];
  #pragma unroll
  for (int e = 0; e < 16; ++e) v1[e] = 0.f;
  float v2 = 0.f;
  float bias2 = (lane < O_DIM) ? b2[lane] : 0.f;

  floatx4 hv[4];
  #pragma unroll
  for (int c = 0; c < 4; ++c) hv[c] = *(const floatx4*)(hrow + c * 256 + lane * 4);

  for (int t = 0; t < T_DIM; ++t) {
    floatx4 hn[4];
    if (t + 1 < T_DIM) {
      #pragma unroll
      for (int c = 0; c < 4; ++c)
        hn[c] = *(const floatx4*)(hrow + (t + 1) * N_DIM + c * 256 + lane * 4);
    }

    float sarr[16];
    #pragma unroll
    for (int c = 0; c < 4; ++c) {
      #pragma unroll
      for (int e = 0; e < 4; ++e) {
        int ii = c * 4 + e;
        float vn = 0.9f * v1[ii] + hv[c][e];
        float s  = 1.f / (1.f + __expf(10.f - 10.f * vn));
        v1[ii] = vn * (1.f - s);
        sarr[ii] = s;
      }
    }

    float part[10];
    #pragma unroll
    for (int o = 0; o < O_DIM; ++o) {
      float a = 0.f;
      #pragma unroll
      for (int c = 0; c < 4; ++c) {
        floatx4 w4 = *(const floatx4*)&w2s[o * N_DIM + c * 256 + lane * 4];
        a += sarr[c * 4 + 0] * w4[0] + sarr[c * 4 + 1] * w4[1]
           + sarr[c * 4 + 2] * w4[2] + sarr[c * 4 + 3] * w4[3];
      }
      part[o] = a;
    }
    #pragma unroll
    for (int m = 1; m < 64; m <<= 1) {
      #pragma unroll
      for (int o = 0; o < O_DIM; ++o) part[o] += __shfl_xor(part[o], m, 64);
    }

    float po = part[0];
    #pragma unroll
    for (int o = 1; o < O_DIM; ++o) po = (lane == o) ? part[o] : po;

    if (lane < O_DIM) {
      float vo = 0.9f * v2 + po + bias2;
      float s2 = 1.f / (1.f + __expf(10.f - 10.f * vo));
      v2 = vo * (1.f - s2);
      orow[t * O_DIM + lane] = s2;
    }

    #pragma unroll
    for (int c = 0; c < 4; ++c) hv[c] = hn[c];
  }
}

extern "C" void kernel_launch(void* const* d_in, const int* in_sizes, int n_in,
                              void* d_out, int out_size, void* d_ws, size_t ws_size,
                              hipStream_t stream) {
  const float* x  = (const float*)d_in[0];
  const float* W1 = (const float*)d_in[1];
  const float* b1 = (const float*)d_in[2];
  const float* W2 = (const float*)d_in[3];
  const float* b2 = (const float*)d_in[4];
  float* out = (float*)d_out;

  float* h = (float*)d_ws;  // 64 MiB

  const size_t H_BYTES  = (size_t)M_DIM * N_DIM * 4;   // 67,108,864
  const size_t WH_BYTES = (size_t)N_DIM * KP * 2;      //  4,849,664
  const size_t NEED = H_BYTES + WH_BYTES;

  if (ws_size >= NEED) {
    _Float16* w1h = (_Float16*)((char*)d_ws + H_BYTES);
    cvt_f32_f16_pad<<<dim3(N_DIM), dim3(256), 0, stream>>>(W1, w1h);
    gemm_fused3<<<dim3(256), dim3(512), 0, stream>>>(x, w1h, b1, h);
  } else {
    gemm1_kernel<<<dim3(1024), dim3(256), 0, stream>>>(x, W1, b1, h);
  }
  snn_temporal_kernel<<<dim3(256), dim3(256), 0, stream>>>(h, W2, b2, out);
}